// Round 8
// baseline (6358.130 us; speedup 1.0000x reference)
//
#include <hip/hip_runtime.h>

typedef unsigned int u32;
typedef _Float16 half_t;
typedef _Float16 half2_t __attribute__((ext_vector_type(2)));

#define B_ 64
#define T_ 2048
#define I_ 128
#define H_ 512
#define O_ 128

static __device__ __forceinline__ float dot2w(u32 w, u32 h, float acc) {
  return __builtin_amdgcn_fdot2(__builtin_bit_cast(half2_t, w),
                                __builtin_bit_cast(half2_t, h), acc, false);
}

// ---------------- K1: pack masked weights to fp16 layouts ----------------
// Whh_pk layout (1024-lane): frag f=j*4+c of lane l at uint4 index f*1024+l.
//   lane l owns rows r_j=(l>>4)*8+j (j=0..7); k-pairs p=(l&15)*16+c*4+w (w=0..3)
__global__ void k_prep(const float* __restrict__ Whh, const float* __restrict__ Mhh,
                       const float* __restrict__ Wih, const float* __restrict__ Mih,
                       const float* __restrict__ Wfc,
                       u32* __restrict__ Whh_pk, u32* __restrict__ Wih_pk,
                       u32* __restrict__ Wfc_pk) {
  int idx = blockIdx.x * 256 + threadIdx.x;
  if (idx < 512 * 256) {
    int f = idx >> 12;            // 0..31
    int l = (idx >> 2) & 1023;
    int w = idx & 3;
    int j = f >> 2, c = f & 3;
    int row = (l >> 4) * 8 + j;
    int p = (l & 15) * 16 + c * 4 + w;
    int k0 = p * 2;
    float a = Whh[row * 512 + k0]     * Mhh[row * 512 + k0];
    float b = Whh[row * 512 + k0 + 1] * Mhh[row * 512 + k0 + 1];
    half2_t hv = { (half_t)a, (half_t)b };
    Whh_pk[idx] = __builtin_bit_cast(u32, hv);
  } else if (idx < 512 * 256 + 512 * 64) {
    int i2 = idx - 512 * 256;
    int h = i2 >> 6, w = i2 & 63;
    int k0 = w * 2;
    float a = Wih[h * 128 + k0]     * Mih[h * 128 + k0];
    float b = Wih[h * 128 + k0 + 1] * Mih[h * 128 + k0 + 1];
    half2_t hv = { (half_t)a, (half_t)b };
    Wih_pk[h * 64 + w] = __builtin_bit_cast(u32, hv);
  } else if (idx < 512 * 256 + 512 * 64 + 128 * 256) {
    int i3 = idx - (512 * 256 + 512 * 64);
    int o = i3 >> 8, w = i3 & 255;
    float a = Wfc[o * 512 + 2 * w];
    float b = Wfc[o * 512 + 2 * w + 1];
    half2_t hv = { (half_t)a, (half_t)b };
    Wfc_pk[o * 256 + w] = __builtin_bit_cast(u32, hv);
  }
}

// ---------------- K2: xproj[b][t][h] = x . Wih_m^T + b_ih + b_hh (fp16 out) ----
__launch_bounds__(512, 2)
__global__ void k_xproj(const float* __restrict__ x, const u32* __restrict__ Wih_pk,
                        const float* __restrict__ b_ih, const float* __restrict__ b_hh,
                        half_t* __restrict__ xp) {
  const int l = threadIdx.x;           // l = h
  const int r0 = blockIdx.x * 256;     // 256 (b,t) rows per block
  __shared__ u32 xb[2][64];
  u32 W[64];
#pragma unroll
  for (int i = 0; i < 16; ++i)
    *(uint4*)&W[i * 4] = *(const uint4*)(Wih_pk + l * 64 + i * 4);
  const float bs = b_ih[l] + b_hh[l];

  float2 g = { 0.f, 0.f };
  if (l < 64) {
    g = *(const float2*)(x + (size_t)r0 * 128 + 2 * l);
    half2_t hv = { (half_t)g.x, (half_t)g.y };
    xb[0][l] = __builtin_bit_cast(u32, hv);
    g = *(const float2*)(x + (size_t)(r0 + 1) * 128 + 2 * l);
  }
  __syncthreads();
  for (int i = 0; i < 256; ++i) {
    if (l < 64 && i + 1 < 256) {
      half2_t hv = { (half_t)g.x, (half_t)g.y };
      xb[(i + 1) & 1][l] = __builtin_bit_cast(u32, hv);
      int nf = (i + 2 < 256) ? i + 2 : i + 1;
      g = *(const float2*)(x + (size_t)(r0 + nf) * 128 + 2 * l);
    }
    float a0 = 0.f, a1 = 0.f;
#pragma unroll
    for (int m = 0; m < 16; ++m) {
      uint4 hv = *(const uint4*)&xb[i & 1][m * 4];
      a0 = dot2w(W[m * 4 + 0], hv.x, a0);
      a1 = dot2w(W[m * 4 + 1], hv.y, a1);
      a0 = dot2w(W[m * 4 + 2], hv.z, a0);
      a1 = dot2w(W[m * 4 + 3], hv.w, a1);
    }
    xp[(size_t)(r0 + i) * 512 + l] = (half_t)(a0 + a1 + bs);
    __syncthreads();
  }
}

// ---------------- K3: recurrence, one 1024-thread block per batch element ----
// Design TO the allocator's de-facto 128-reg/4-waves-per-EU budget (r2-r7:
// every attempt above it was hard-spilled): 1024 lanes -> 128 u32 weights per
// lane; 96 resident in 24 named laundered uint4 frags (393 KB/CU in registers),
// 32 u32/lane streamed from L2 per step (128 KB/CU/step ~ 1100 cyc, overlapped
// with ~1400 cyc VALU). 16-lane k-groups (32 ks), 8 rows/lane, 4-level
// keep-half butterfly; lane finalizes row (l>>4)*8+(l&7), bit3==0 stores.
// hs aliases xp (read-before-write per t with 2-deep prefetch).
#define WPLD(N, F) u32 N##_x, N##_y, N##_z, N##_w; \
  { uint4 t_ = wpk4[(F) * 1024 + l]; \
    N##_x = t_.x; N##_y = t_.y; N##_z = t_.z; N##_w = t_.w; }
#define LNDF(N) asm volatile("" : "+v"(N##_x), "+v"(N##_y), "+v"(N##_z), "+v"(N##_w));
#define DOTR(Jn, N) { acc[Jn] = dot2w(N##_x, hh.x, acc[Jn]); acc[Jn] = dot2w(N##_y, hh.y, acc[Jn]); \
                      acc[Jn] = dot2w(N##_z, hh.z, acc[Jn]); acc[Jn] = dot2w(N##_w, hh.w, acc[Jn]); }
#define DOTU(Jn, V) { acc[Jn] = dot2w((V).x, hh.x, acc[Jn]); acc[Jn] = dot2w((V).y, hh.y, acc[Jn]); \
                      acc[Jn] = dot2w((V).z, hh.z, acc[Jn]); acc[Jn] = dot2w((V).w, hh.w, acc[Jn]); }
#define ISS(c) const uint4* p##c = wst; asm volatile("" : "+v"(p##c)); \
  uint4 s6_##c = p##c[(24 + c) * 1024]; uint4 s7_##c = p##c[(28 + c) * 1024];
#define BLK(c) { uint4 hh = *(const uint4*)&hbc[g * 20 + c * 4]; \
  DOTR(0, W0_##c) DOTR(1, W1_##c) DOTR(2, W2_##c) DOTR(3, W3_##c) \
  DOTR(4, W4_##c) DOTR(5, W5_##c) DOTU(6, s6_##c) DOTU(7, s7_##c) }

__global__ void __launch_bounds__(1024)
k_rec(const u32* __restrict__ Whh_pk, half_t* __restrict__ xp,
      const float* __restrict__ h0) {
  const int b = blockIdx.x;
  const int l = threadIdx.x;            // 0..1023
  const int g = l & 15;                 // k-group: ks [g*32, g*32+32)

  __shared__ u32 hbuf[2][320];          // 16-word chunks padded to 20 (2-way max)

  const uint4* wpk4 = (const uint4*)Whh_pk;

  // 24 register-resident frags: (j,c) for j=0..5, c=0..3  (f = j*4+c)
  WPLD(W0_0, 0)  WPLD(W0_1, 1)  WPLD(W0_2, 2)  WPLD(W0_3, 3)
  WPLD(W1_0, 4)  WPLD(W1_1, 5)  WPLD(W1_2, 6)  WPLD(W1_3, 7)
  WPLD(W2_0, 8)  WPLD(W2_1, 9)  WPLD(W2_2, 10) WPLD(W2_3, 11)
  WPLD(W3_0, 12) WPLD(W3_1, 13) WPLD(W3_2, 14) WPLD(W3_3, 15)
  WPLD(W4_0, 16) WPLD(W4_1, 17) WPLD(W4_2, 18) WPLD(W4_3, 19)
  WPLD(W5_0, 20) WPLD(W5_1, 21) WPLD(W5_2, 22) WPLD(W5_3, 23)
  LNDF(W0_0) LNDF(W0_1) LNDF(W0_2) LNDF(W0_3)
  LNDF(W1_0) LNDF(W1_1) LNDF(W1_2) LNDF(W1_3)
  LNDF(W2_0) LNDF(W2_1) LNDF(W2_2) LNDF(W2_3)
  LNDF(W3_0) LNDF(W3_1) LNDF(W3_2) LNDF(W3_3)
  LNDF(W4_0) LNDF(W4_1) LNDF(W4_2) LNDF(W4_3)
  LNDF(W5_0) LNDF(W5_1) LNDF(W5_2) LNDF(W5_3)

  // initial h from h0: word w -> padded addr (w>>4)*20 + (w&15)
  if (l < 256) {
    float2 hv = *(const float2*)(h0 + (size_t)b * 512 + 2 * l);
    half2_t hh = { (half_t)hv.x, (half_t)hv.y };
    hbuf[0][(l >> 4) * 20 + (l & 15)] = __builtin_bit_cast(u32, hh);
  }
  __syncthreads();

  const uint4* wst = wpk4 + l;                       // streamed-frag base

  const int rfin = (l >> 4) * 8 + (l & 7);           // row this lane finalizes
  half_t* xpb = xp + (size_t)b * T_ * 512 + rfin;
  half_t xp0 = xpb[0];
  half_t xp1 = xpb[512];

  const int b0 = l & 1, b1 = (l >> 1) & 1, b2 = (l >> 2) & 1;
  const int storer = ((l & 8) == 0);
  const int wIdx = rfin >> 1;
  const int pa = (wIdx >> 4) * 20 + (wIdx & 15);     // padded word of rfin's half
  int cur = 0;

  for (int t = 0; t < T_; ++t) {
    const u32* hbc = hbuf[cur];

    ISS(0) ISS(1)                                    // 2 frag-groups in flight

    int tpf = (t + 2 < T_) ? t + 2 : T_ - 1;
    half_t xpn = xpb[(size_t)tpf * 512];             // xp prefetch, 2 steps ahead

    float acc[8];
#pragma unroll
    for (int j = 0; j < 8; ++j) acc[j] = 0.f;

    BLK(0) ISS(2)
    BLK(1) ISS(3)
    BLK(2)
    BLK(3)

    // keep-half butterfly: 4 levels over the 16-lane k-group
    float s4[4];
#pragma unroll
    for (int m = 0; m < 4; ++m) {
      float keep = b0 ? acc[2 * m + 1] : acc[2 * m];
      float send = b0 ? acc[2 * m]     : acc[2 * m + 1];
      s4[m] = keep + __shfl_xor(send, 1, 64);
    }
    float s2[2];
#pragma unroll
    for (int m = 0; m < 2; ++m) {
      float keep = b1 ? s4[2 * m + 1] : s4[2 * m];
      float send = b1 ? s4[2 * m]     : s4[2 * m + 1];
      s2[m] = keep + __shfl_xor(send, 2, 64);
    }
    float keepf = b2 ? s2[1] : s2[0];
    float sendf = b2 ? s2[0] : s2[1];
    float s1 = keepf + __shfl_xor(sendf, 4, 64);
    float tot = s1 + __shfl_xor(s1, 8, 64);          // combine k-halves (bit3)

    float sarg = tot + (float)xp0;
    float ax = fabsf(sarg);
    float e = __expf(-2.f * ax);
    float r = (1.f - e) * __builtin_amdgcn_rcpf(1.f + e);
    float hval = copysignf(r, sarg);
    half_t hv = (half_t)hval;

    if (storer) {
      ((half_t*)hbuf[cur ^ 1])[pa * 2 + (rfin & 1)] = hv;
      xpb[(size_t)t * 512] = hv;        // overwrite consumed xproj slot with h
    }

    xp0 = xp1; xp1 = xpn;
    __syncthreads();
    cur ^= 1;
  }
}

// ---------------- K4: readout out[b][t][o] = hs . Wfc^T + b_fc ----------------
__launch_bounds__(256, 2)
__global__ void k_fc(const half_t* __restrict__ hs, const u32* __restrict__ Wfc_pk,
                     const float* __restrict__ b_fc, float* __restrict__ out) {
  const int l = threadIdx.x;
  const int w = l >> 6;                       // wave 0..3
  const int o = (l & 31) + w * 32;
  const int kh = (l >> 5) & 1;                // k half
  const int r0 = blockIdx.x * 256;
  __shared__ u32 sb[2][256];
  u32 W[128];
#pragma unroll
  for (int i = 0; i < 32; ++i)
    *(uint4*)&W[i * 4] = *(const uint4*)(Wfc_pk + o * 256 + kh * 128 + i * 4);
  const float bf = b_fc[o];
  const u32* hsw = (const u32*)hs;

  u32 gA = hsw[(size_t)r0 * 256 + l];
  sb[0][l] = gA;
  gA = hsw[(size_t)(r0 + 1) * 256 + l];
  __syncthreads();
  for (int i = 0; i < 256; ++i) {
    if (i + 1 < 256) {
      sb[(i + 1) & 1][l] = gA;
      int nf = (i + 2 < 256) ? i + 2 : i + 1;
      gA = hsw[(size_t)(r0 + nf) * 256 + l];
    }
    float a0 = 0.f, a1 = 0.f;
#pragma unroll
    for (int m = 0; m < 32; ++m) {
      uint4 hv = *(const uint4*)&sb[i & 1][kh * 128 + m * 4];
      a0 = dot2w(W[m * 4 + 0], hv.x, a0);
      a1 = dot2w(W[m * 4 + 1], hv.y, a1);
      a0 = dot2w(W[m * 4 + 2], hv.z, a0);
      a1 = dot2w(W[m * 4 + 3], hv.w, a1);
    }
    float a = a0 + a1;
    a += __shfl_xor(a, 32, 64);
    if (kh == 0) out[(size_t)(r0 + i) * 128 + o] = a + bf;
    __syncthreads();
  }
}

extern "C" void kernel_launch(void* const* d_in, const int* in_sizes, int n_in,
                              void* d_out, int out_size, void* d_ws, size_t ws_size,
                              hipStream_t stream) {
  const float* x   = (const float*)d_in[0];
  const float* h0  = (const float*)d_in[1];
  const float* Wih = (const float*)d_in[2];
  const float* bih = (const float*)d_in[3];
  const float* Whh = (const float*)d_in[4];
  const float* bhh = (const float*)d_in[5];
  const float* Mih = (const float*)d_in[6];
  const float* Mhh = (const float*)d_in[7];
  const float* Wfc = (const float*)d_in[8];
  const float* bfc = (const float*)d_in[9];
  float* out = (float*)d_out;

  char* ws = (char*)d_ws;
  // layout (total ~128.8 MB):
  //   xproj/hs shared fp16 buffer (128 MB) | Whh_pk (512KB) | Wih_pk (128KB) | Wfc_pk (128KB)
  half_t* xproj = (half_t*)(ws);                         // aliased: becomes hs after k_rec
  u32* Whh_pk = (u32*)(ws + 134217728);
  u32* Wih_pk = (u32*)(ws + 134217728 + 524288);
  u32* Wfc_pk = (u32*)(ws + 134217728 + 524288 + 131072);

  hipLaunchKernelGGL(k_prep, dim3(768), dim3(256), 0, stream,
                     Whh, Mhh, Wih, Mih, Wfc, Whh_pk, Wih_pk, Wfc_pk);
  hipLaunchKernelGGL(k_xproj, dim3(512), dim3(512), 0, stream,
                     x, Wih_pk, bih, bhh, xproj);
  hipLaunchKernelGGL(k_rec, dim3(64), dim3(1024), 0, stream,
                     Whh_pk, xproj, h0);
  hipLaunchKernelGGL(k_fc, dim3(512), dim3(256), 0, stream,
                     xproj, Wfc_pk, bfc, out);
}

// Round 9
// 6296.133 us; speedup vs baseline: 1.0098x; 1.0098x over previous
//
#include <hip/hip_runtime.h>

typedef unsigned int u32;
typedef _Float16 half_t;
typedef _Float16 half2_t __attribute__((ext_vector_type(2)));

#define B_ 64
#define T_ 2048
#define I_ 128
#define H_ 512
#define O_ 128

static __device__ __forceinline__ float dot2w(u32 w, u32 h, float acc) {
  return __builtin_amdgcn_fdot2(__builtin_bit_cast(half2_t, w),
                                __builtin_bit_cast(half2_t, h), acc, false);
}

// ---------------- K1: pack masked weights to fp16 layouts ----------------
// Whh_pk layout: word q (=j*32+m) of lane l stored at [ (q/4)*2048 + l*4 + (q&3) ]
//   lane l owns rows r_j = (l>>3)*8 + j (j=0..7), k-range [ (l&7)*64, +64 )
__global__ void k_prep(const float* __restrict__ Whh, const float* __restrict__ Mhh,
                       const float* __restrict__ Wih, const float* __restrict__ Mih,
                       const float* __restrict__ Wfc,
                       u32* __restrict__ Whh_pk, u32* __restrict__ Wih_pk,
                       u32* __restrict__ Wfc_pk) {
  int idx = blockIdx.x * 256 + threadIdx.x;
  if (idx < 512 * 256) {
    int w4 = idx >> 11;
    int rem = idx & 2047;
    int l = rem >> 2;
    int c = rem & 3;
    int q = w4 * 4 + c;
    int j = q >> 5;
    int m = q & 31;
    int row = (l >> 3) * 8 + j;
    int k0 = (l & 7) * 64 + m * 2;
    float a = Whh[row * 512 + k0]     * Mhh[row * 512 + k0];
    float b = Whh[row * 512 + k0 + 1] * Mhh[row * 512 + k0 + 1];
    half2_t hv = { (half_t)a, (half_t)b };
    Whh_pk[idx] = __builtin_bit_cast(u32, hv);
  } else if (idx < 512 * 256 + 512 * 64) {
    int i2 = idx - 512 * 256;
    int h = i2 >> 6, w = i2 & 63;
    int k0 = w * 2;
    float a = Wih[h * 128 + k0]     * Mih[h * 128 + k0];
    float b = Wih[h * 128 + k0 + 1] * Mih[h * 128 + k0 + 1];
    half2_t hv = { (half_t)a, (half_t)b };
    Wih_pk[h * 64 + w] = __builtin_bit_cast(u32, hv);
  } else if (idx < 512 * 256 + 512 * 64 + 128 * 256) {
    int i3 = idx - (512 * 256 + 512 * 64);
    int o = i3 >> 8, w = i3 & 255;
    float a = Wfc[o * 512 + 2 * w];
    float b = Wfc[o * 512 + 2 * w + 1];
    half2_t hv = { (half_t)a, (half_t)b };
    Wfc_pk[o * 256 + w] = __builtin_bit_cast(u32, hv);
  }
}

// ---------------- K2: xproj[b][t][h] = x . Wih_m^T + b_ih + b_hh (fp16 out) ----
__launch_bounds__(512, 2)
__global__ void k_xproj(const float* __restrict__ x, const u32* __restrict__ Wih_pk,
                        const float* __restrict__ b_ih, const float* __restrict__ b_hh,
                        half_t* __restrict__ xp) {
  const int l = threadIdx.x;           // l = h
  const int r0 = blockIdx.x * 256;     // 256 (b,t) rows per block
  __shared__ u32 xb[2][64];
  u32 W[64];
#pragma unroll
  for (int i = 0; i < 16; ++i)
    *(uint4*)&W[i * 4] = *(const uint4*)(Wih_pk + l * 64 + i * 4);
  const float bs = b_ih[l] + b_hh[l];

  float2 g = { 0.f, 0.f };
  if (l < 64) {
    g = *(const float2*)(x + (size_t)r0 * 128 + 2 * l);
    half2_t hv = { (half_t)g.x, (half_t)g.y };
    xb[0][l] = __builtin_bit_cast(u32, hv);
    g = *(const float2*)(x + (size_t)(r0 + 1) * 128 + 2 * l);
  }
  __syncthreads();
  for (int i = 0; i < 256; ++i) {
    if (l < 64 && i + 1 < 256) {
      half2_t hv = { (half_t)g.x, (half_t)g.y };
      xb[(i + 1) & 1][l] = __builtin_bit_cast(u32, hv);
      int nf = (i + 2 < 256) ? i + 2 : i + 1;
      g = *(const float2*)(x + (size_t)(r0 + nf) * 128 + 2 * l);
    }
    float a0 = 0.f, a1 = 0.f;
#pragma unroll
    for (int m = 0; m < 16; ++m) {
      uint4 hv = *(const uint4*)&xb[i & 1][m * 4];
      a0 = dot2w(W[m * 4 + 0], hv.x, a0);
      a1 = dot2w(W[m * 4 + 1], hv.y, a1);
      a0 = dot2w(W[m * 4 + 2], hv.z, a0);
      a1 = dot2w(W[m * 4 + 3], hv.w, a1);
    }
    xp[(size_t)(r0 + i) * 512 + l] = (half_t)(a0 + a1 + bs);
    __syncthreads();
  }
}

// ---------------- K3: recurrence, one block per batch element ----------------
// Budget-aware 3-way weight split, designed TO the allocator's de-facto
// 128-reg budget (r2-r8: pinning above it always scratch-spills):
//   - 16 uint4/lane (64 u32) plain named regs, NO launder: pressure ~125 <= 128
//     so the compiler has no incentive to spill/remat.
//   - 19 uint4/lane in LDS (152 KB), contiguous-16B ds_read_b128; per-iteration
//     laundered index wq blocks cross-iteration hoisting of 76 u32.
//   - 29 uint4/lane streamed from L2 (237 KB/CU/step @ ~117 B/cyc), pipelined
//     2 m4-clusters ahead; per-cluster laundered pointer blocks CSE/hoist.
// hs aliases xp (read xpc at top of step t, overwrite at bottom; disjoint b).
#define WPLD(N, F) u32 N##_x, N##_y, N##_z, N##_w; \
  { uint4 t_ = wpk4[(F) * 512 + l]; \
    N##_x = t_.x; N##_y = t_.y; N##_z = t_.z; N##_w = t_.w; }
#define DOTR(Jn, N) { acc[Jn] = dot2w(N##_x, hh.x, acc[Jn]); acc[Jn] = dot2w(N##_y, hh.y, acc[Jn]); \
                      acc[Jn] = dot2w(N##_z, hh.z, acc[Jn]); acc[Jn] = dot2w(N##_w, hh.w, acc[Jn]); }
#define DOTU(Jn, V) { acc[Jn] = dot2w((V).x, hh.x, acc[Jn]); acc[Jn] = dot2w((V).y, hh.y, acc[Jn]); \
                      acc[Jn] = dot2w((V).z, hh.z, acc[Jn]); acc[Jn] = dot2w((V).w, hh.w, acc[Jn]); }
#define ISSA(c) const uint4* p##c = wst; asm volatile("" : "+v"(p##c)); \
  uint4 s5_##c = p##c[(40 + c) * 512]; uint4 s6_##c = p##c[(48 + c) * 512]; \
  uint4 s7_##c = p##c[(56 + c) * 512];
#define ISSB(c) const uint4* p##c = wst; asm volatile("" : "+v"(p##c)); \
  uint4 s4_##c = p##c[(32 + c) * 512]; \
  uint4 s5_##c = p##c[(40 + c) * 512]; uint4 s6_##c = p##c[(48 + c) * 512]; \
  uint4 s7_##c = p##c[(56 + c) * 512];
#define BLKA(M) { uint4 hh = *(const uint4*)&hbc[g * 36 + M * 4]; \
  uint4 v2 = wlds4[(M) * 512 + wq]; uint4 v3 = wlds4[(8 + M) * 512 + wq]; \
  uint4 v4 = wlds4[(16 + M) * 512 + wq]; \
  DOTR(0, W0_##M) DOTR(1, W1_##M) DOTU(2, v2) DOTU(3, v3) DOTU(4, v4) \
  DOTU(5, s5_##M) DOTU(6, s6_##M) DOTU(7, s7_##M) }
#define BLKB(M) { uint4 hh = *(const uint4*)&hbc[g * 36 + M * 4]; \
  uint4 v2 = wlds4[(M) * 512 + wq]; uint4 v3 = wlds4[(8 + M) * 512 + wq]; \
  DOTR(0, W0_##M) DOTR(1, W1_##M) DOTU(2, v2) DOTU(3, v3) DOTU(4, s4_##M) \
  DOTU(5, s5_##M) DOTU(6, s6_##M) DOTU(7, s7_##M) }

__global__ void __launch_bounds__(512)
k_rec(const u32* __restrict__ Whh_pk, half_t* __restrict__ xp,
      const float* __restrict__ h0) {
  const int b = blockIdx.x;
  const int l = threadIdx.x;
  const int g = l & 7;                  // k-group: k in [g*64, g*64+64)

  __shared__ u32 hbuf[2][288];          // h fp16 packed; 32-word chunks padded +4
  __shared__ uint4 wlds4[19 * 512];     // 152 KB LDS-resident weight frags

  const uint4* wpk4 = (const uint4*)Whh_pk;

  // 16 register-resident frags (plain, unlaundered): rows j=0,1, all m4
  WPLD(W0_0, 0)  WPLD(W0_1, 1)  WPLD(W0_2, 2)  WPLD(W0_3, 3)
  WPLD(W0_4, 4)  WPLD(W0_5, 5)  WPLD(W0_6, 6)  WPLD(W0_7, 7)
  WPLD(W1_0, 8)  WPLD(W1_1, 9)  WPLD(W1_2, 10) WPLD(W1_3, 11)
  WPLD(W1_4, 12) WPLD(W1_5, 13) WPLD(W1_6, 14) WPLD(W1_7, 15)

  // LDS frags: j=2 -> q=0..7, j=3 -> q=8..15, j=4 m4=0..2 -> q=16..18
#pragma unroll
  for (int m4 = 0; m4 < 8; ++m4) {
    wlds4[m4 * 512 + l]       = wpk4[(16 + m4) * 512 + l];
    wlds4[(8 + m4) * 512 + l] = wpk4[(24 + m4) * 512 + l];
  }
#pragma unroll
  for (int m4 = 0; m4 < 3; ++m4)
    wlds4[(16 + m4) * 512 + l] = wpk4[(32 + m4) * 512 + l];

  // initial h from h0 (padded-chunk layout: word w goes to w + (w/32)*4)
  if (l < 256) {
    float2 hv = *(const float2*)(h0 + (size_t)b * 512 + 2 * l);
    half2_t hh = { (half_t)hv.x, (half_t)hv.y };
    hbuf[0][l + (l >> 5) * 4] = __builtin_bit_cast(u32, hh);
  }
  __syncthreads();

  const uint4* wst = wpk4 + l;                       // streamed-frag base

  half_t* xpb = xp + (size_t)b * T_ * 512 + l;       // row == l
  const int b0 = l & 1, b1 = (l >> 1) & 1, b2 = (l >> 2) & 1;
  const int hwIdx = (l >> 1) + (l >> 6) * 4;         // padded word idx of row's half
  int cur = 0;

  for (int t = 0; t < T_; ++t) {
    const u32* hbc = hbuf[cur];
    u32 wq = l; asm volatile("" : "+v"(wq));         // per-iter opaque LDS index
    half_t xpc = xpb[(size_t)t * 512];               // read before overwrite below

    ISSA(0) ISSA(1)                                  // 2 stream-clusters in flight

    float acc[8];
#pragma unroll
    for (int j = 0; j < 8; ++j) acc[j] = 0.f;

    BLKA(0) ISSA(2)
    BLKA(1) ISSB(3)
    BLKA(2) ISSB(4)
    BLKB(3) ISSB(5)
    BLKB(4) ISSB(6)
    BLKB(5) ISSB(7)
    BLKB(6)
    BLKB(7)

    // keep-half butterfly over the 8-lane k-group dim; lane l ends with row l total
    float s4[4];
#pragma unroll
    for (int m = 0; m < 4; ++m) {
      float keep = b0 ? acc[2 * m + 1] : acc[2 * m];
      float send = b0 ? acc[2 * m]     : acc[2 * m + 1];
      s4[m] = keep + __shfl_xor(send, 1, 64);
    }
    float s2[2];
#pragma unroll
    for (int m = 0; m < 2; ++m) {
      float keep = b1 ? s4[2 * m + 1] : s4[2 * m];
      float send = b1 ? s4[2 * m]     : s4[2 * m + 1];
      s2[m] = keep + __shfl_xor(send, 2, 64);
    }
    float keepf = b2 ? s2[1] : s2[0];
    float sendf = b2 ? s2[0] : s2[1];
    float tot = keepf + __shfl_xor(sendf, 4, 64);

    float sarg = tot + (float)xpc;
    float ax = fabsf(sarg);
    float e = __expf(-2.f * ax);
    float r = (1.f - e) * __builtin_amdgcn_rcpf(1.f + e);
    float hval = copysignf(r, sarg);

    half_t hv = (half_t)hval;
    ((half_t*)hbuf[cur ^ 1])[hwIdx * 2 + (l & 1)] = hv;
    xpb[(size_t)t * 512] = hv;            // overwrite consumed xproj slot with h

    __syncthreads();
    cur ^= 1;
  }
}

// ---------------- K4: readout out[b][t][o] = hs . Wfc^T + b_fc ----------------
__launch_bounds__(256, 2)
__global__ void k_fc(const half_t* __restrict__ hs, const u32* __restrict__ Wfc_pk,
                     const float* __restrict__ b_fc, float* __restrict__ out) {
  const int l = threadIdx.x;
  const int w = l >> 6;                       // wave 0..3
  const int o = (l & 31) + w * 32;
  const int kh = (l >> 5) & 1;                // k half
  const int r0 = blockIdx.x * 256;
  __shared__ u32 sb[2][256];
  u32 W[128];
#pragma unroll
  for (int i = 0; i < 32; ++i)
    *(uint4*)&W[i * 4] = *(const uint4*)(Wfc_pk + o * 256 + kh * 128 + i * 4);
  const float bf = b_fc[o];
  const u32* hsw = (const u32*)hs;

  u32 gA = hsw[(size_t)r0 * 256 + l];
  sb[0][l] = gA;
  gA = hsw[(size_t)(r0 + 1) * 256 + l];
  __syncthreads();
  for (int i = 0; i < 256; ++i) {
    if (i + 1 < 256) {
      sb[(i + 1) & 1][l] = gA;
      int nf = (i + 2 < 256) ? i + 2 : i + 1;
      gA = hsw[(size_t)(r0 + nf) * 256 + l];
    }
    float a0 = 0.f, a1 = 0.f;
#pragma unroll
    for (int m = 0; m < 32; ++m) {
      uint4 hv = *(const uint4*)&sb[i & 1][kh * 128 + m * 4];
      a0 = dot2w(W[m * 4 + 0], hv.x, a0);
      a1 = dot2w(W[m * 4 + 1], hv.y, a1);
      a0 = dot2w(W[m * 4 + 2], hv.z, a0);
      a1 = dot2w(W[m * 4 + 3], hv.w, a1);
    }
    float a = a0 + a1;
    a += __shfl_xor(a, 32, 64);
    if (kh == 0) out[(size_t)(r0 + i) * 128 + o] = a + bf;
    __syncthreads();
  }
}

extern "C" void kernel_launch(void* const* d_in, const int* in_sizes, int n_in,
                              void* d_out, int out_size, void* d_ws, size_t ws_size,
                              hipStream_t stream) {
  const float* x   = (const float*)d_in[0];
  const float* h0  = (const float*)d_in[1];
  const float* Wih = (const float*)d_in[2];
  const float* bih = (const float*)d_in[3];
  const float* Whh = (const float*)d_in[4];
  const float* bhh = (const float*)d_in[5];
  const float* Mih = (const float*)d_in[6];
  const float* Mhh = (const float*)d_in[7];
  const float* Wfc = (const float*)d_in[8];
  const float* bfc = (const float*)d_in[9];
  float* out = (float*)d_out;

  char* ws = (char*)d_ws;
  // layout (total ~128.8 MB):
  //   xproj/hs shared fp16 buffer (128 MB) | Whh_pk (512KB) | Wih_pk (128KB) | Wfc_pk (128KB)
  half_t* xproj = (half_t*)(ws);                         // aliased: becomes hs after k_rec
  u32* Whh_pk = (u32*)(ws + 134217728);
  u32* Wih_pk = (u32*)(ws + 134217728 + 524288);
  u32* Wfc_pk = (u32*)(ws + 134217728 + 524288 + 131072);

  hipLaunchKernelGGL(k_prep, dim3(768), dim3(256), 0, stream,
                     Whh, Mhh, Wih, Mih, Wfc, Whh_pk, Wih_pk, Wfc_pk);
  hipLaunchKernelGGL(k_xproj, dim3(512), dim3(512), 0, stream,
                     x, Wih_pk, bih, bhh, xproj);
  hipLaunchKernelGGL(k_rec, dim3(64), dim3(512), 0, stream,
                     Whh_pk, xproj, h0);
  hipLaunchKernelGGL(k_fc, dim3(512), dim3(256), 0, stream,
                     xproj, Wfc_pk, bfc, out);
}